// Round 11
// baseline (521.538 us; speedup 1.0000x reference)
//
#include <hip/hip_runtime.h>
#include <hip/hip_bf16.h>

#define Tt   16384
#define Dd   1024
#define Ee   8
#define CAP  2048
#define DFFf 4096

typedef __attribute__((ext_vector_type(8))) short bf16x8;
typedef __attribute__((ext_vector_type(16))) float f32x16;

__device__ __forceinline__ unsigned short f2bf(float f) {
  union { float f; unsigned u; } v; v.f = f;
  unsigned r = (v.u + 0x7FFFu + ((v.u >> 16) & 1u)) >> 16;
  return (unsigned short)r;
}

__device__ __forceinline__ float gelu_tanh(float x) {
  float z = 0.7978845608028654f * (x + 0.044715f * x * x * x);
  float az = fabsf(z);
  float t = __expf(-2.0f * az);
  float th = (1.0f - t) / (1.0f + t);
  th = (z < 0.0f) ? -th : th;
  return 0.5f * x * (1.0f + th);
}

__device__ __forceinline__ void gld16(const void* g, void* l) {
  __builtin_amdgcn_global_load_lds(
      (const __attribute__((address_space(1))) void*)g,
      (__attribute__((address_space(3))) void*)l,
      16, 0, 0);
}

template <int IMM>
__device__ __forceinline__ bf16x8 dsr(unsigned a) {
  bf16x8 r;
  asm volatile("ds_read_b128 %0, %1 offset:%c2" : "=v"(r) : "v"(a), "i"(IMM));
  return r;
}
#define LGKM(N) asm volatile("s_waitcnt lgkmcnt(" #N ")" ::: "memory")
#define VMCNT(N) asm volatile("s_waitcnt vmcnt(" #N ")" ::: "memory")

// ---------------- gating: logits fp32, softmax, argmax ----------------
__global__ __launch_bounds__(256) void gating_kernel(
    const float* __restrict__ x, const float* __restrict__ wg,
    int* __restrict__ idx, float* __restrict__ gate, float* __restrict__ meP) {
  int tid = threadIdx.x, lane = tid & 63, w = tid >> 6;
  int t = blockIdx.x * 4 + w;
  const float* xr = x + (size_t)t * Dd;
  float p[8];
#pragma unroll
  for (int e2 = 0; e2 < 8; ++e2) p[e2] = 0.f;
#pragma unroll
  for (int i = 0; i < 16; ++i) {
    int j = lane + (i << 6);
    float xv = xr[j];
    const float4* wr = (const float4*)(wg + j * 8);
    float4 a = wr[0], b = wr[1];
    p[0] += xv * a.x; p[1] += xv * a.y; p[2] += xv * a.z; p[3] += xv * a.w;
    p[4] += xv * b.x; p[5] += xv * b.y; p[6] += xv * b.z; p[7] += xv * b.w;
  }
#pragma unroll
  for (int off = 32; off > 0; off >>= 1)
#pragma unroll
    for (int e2 = 0; e2 < 8; ++e2) p[e2] += __shfl_xor(p[e2], off);
  __shared__ float smG[4][8];
  if (lane == 0) {
    float mx = p[0]; int am = 0;
#pragma unroll
    for (int e2 = 1; e2 < 8; ++e2) if (p[e2] > mx) { mx = p[e2]; am = e2; }
    float s = 0.f, g2[8];
#pragma unroll
    for (int e2 = 0; e2 < 8; ++e2) { g2[e2] = __expf(p[e2] - mx); s += g2[e2]; }
    float inv = 1.f / s;
    idx[t] = am;
    gate[t] = g2[am] * inv;
#pragma unroll
    for (int e2 = 0; e2 < 8; ++e2) smG[w][e2] = g2[e2] * inv;
  }
  __syncthreads();
  if (tid < 8)
    meP[blockIdx.x * 8 + tid] = smG[0][tid] + smG[1][tid] + smG[2][tid] + smG[3][tid];
}

// ------------- parallel scan, stage 1: per-chunk expert counts -------------
__global__ __launch_bounds__(256) void count_kernel(
    const int* __restrict__ idx, int* __restrict__ cnt) {
  int tid = threadIdx.x, lane = tid & 63, w = tid >> 6;
  int e = idx[blockIdx.x * 256 + tid];
  __shared__ int c[4][8];
#pragma unroll
  for (int q = 0; q < 8; ++q) {
    unsigned long long m = __ballot(e == q);
    if (lane == 0) c[w][q] = (int)__popcll(m);
  }
  __syncthreads();
  if (tid < 8)
    cnt[blockIdx.x * 8 + tid] = c[0][tid] + c[1][tid] + c[2][tid] + c[3][tid];
}

// ------------- stage 2: exclusive prefix over chunks + l_aux -------------
__global__ __launch_bounds__(256) void prefix_kernel(
    const int* __restrict__ cnt, int* __restrict__ base,
    const float* __restrict__ meP, float* __restrict__ laux_out) {
  int tid = threadIdx.x;
  __shared__ int tot[8];
  __shared__ float red[256];
  __shared__ float smes[8];
  if (tid < 8) {
    int run = 0;
    for (int b2 = 0; b2 < 64; ++b2) { base[b2 * 8 + tid] = run; run += cnt[b2 * 8 + tid]; }
    tot[tid] = run;
  }
  float part = 0.f;
  int e2 = tid & 7, r0 = tid >> 3;
  for (int b2 = r0; b2 < 4096; b2 += 32) part += meP[b2 * 8 + e2];
  red[tid] = part;
  __syncthreads();
  if (tid < 8) {
    float s = 0.f;
    for (int i = 0; i < 32; ++i) s += red[i * 8 + tid];
    smes[tid] = s * (float)tot[tid];
  }
  __syncthreads();
  if (tid == 0) {
    float l = 0.f;
    for (int q = 0; q < 8; ++q) l += smes[q];
    laux_out[0] = l * 8.0f / ((float)Tt * (float)Tt);
  }
}

// ------------- stage 3: assign positions + slot map -------------
__global__ __launch_bounds__(256) void assign_kernel(
    const int* __restrict__ idx, const int* __restrict__ base,
    int* __restrict__ pos, int* __restrict__ smap) {
  int tid = threadIdx.x, lane = tid & 63, w = tid >> 6;
  int t = blockIdx.x * 256 + tid;
  int e = idx[t];
  __shared__ int wc[4][8];
  int myoff = 0;
#pragma unroll
  for (int q = 0; q < 8; ++q) {
    unsigned long long m = __ballot(e == q);
    if (lane == 0) wc[w][q] = (int)__popcll(m);
    if (e == q) myoff = (int)__popcll(m & ((1ull << lane) - 1ull));
  }
  __syncthreads();
  int b = base[blockIdx.x * 8 + e];
  for (int ww = 0; ww < w; ++ww) b += wc[ww][e];
  int p = b + myoff;
  pos[t] = p;
  if (p < CAP) smap[e * CAP + p] = t;
}

// ------------- zero dropped-token output rows (grid-stride) -------------
__global__ __launch_bounds__(256) void zero_dropped(
    const int* __restrict__ pos, float* __restrict__ out) {
  for (int t = blockIdx.x; t < Tt; t += gridDim.x) {
    if (pos[t] < CAP) continue;
    ((float4*)(out + (size_t)t * Dd))[threadIdx.x] = make_float4(0.f, 0.f, 0.f, 0.f);
  }
}

// ------------- merged transpose + cast fp32 -> bf16 (both weights) ----------
__global__ __launch_bounds__(256) void transpose_cast2(
    const float* __restrict__ w1, const float* __restrict__ w2,
    unsigned short* __restrict__ W1T, unsigned short* __restrict__ W2T) {
  __shared__ float tile[64][65];
  int z = blockIdx.z, tz = blockIdx.x;
  const float* s; unsigned short* d; int R, Cn, rb, cb;
  if (z < 8) {
    s = w1 + (size_t)z * Dd * DFFf; d = W1T + (size_t)z * Dd * DFFf;
    R = Dd; Cn = DFFf; rb = (tz >> 6) * 64; cb = (tz & 63) * 64;
  } else {
    s = w2 + (size_t)(z - 8) * DFFf * Dd; d = W2T + (size_t)(z - 8) * DFFf * Dd;
    R = DFFf; Cn = Dd; rb = (tz >> 4) * 64; cb = (tz & 15) * 64;
  }
  int c = threadIdx.x & 63;
  int r0 = threadIdx.x >> 6;
#pragma unroll
  for (int i = 0; i < 16; ++i) {
    int r = r0 + i * 4;
    tile[r][c] = s[(size_t)(rb + r) * Cn + cb + c];
  }
  __syncthreads();
#pragma unroll
  for (int i = 0; i < 16; ++i) {
    int r = r0 + i * 4;
    d[(size_t)(cb + r) * R + rb + c] = f2bf(tile[c][r]);
  }
}

// ------------- gather + cast dispatched tokens -------------
__global__ __launch_bounds__(256) void build_xg(
    const float* __restrict__ x, const int* __restrict__ smap,
    unsigned short* __restrict__ Xg) {
  int row = blockIdx.x;
  int t = smap[row];
  int j = threadIdx.x;
  float4 v = make_float4(0.f, 0.f, 0.f, 0.f);
  if (t >= 0) v = ((const float4*)(x + (size_t)t * Dd))[j];
  ushort4 o;
  o.x = f2bf(v.x); o.y = f2bf(v.y); o.z = f2bf(v.z); o.w = f2bf(v.w);
  ((ushort4*)(Xg + (size_t)row * Dd))[j] = o;
}

// ------ 256^2-tile bf16 MFMA GEMM (B^T), 32x32x16 shape, BK=64 dbuf ---------
// 8 waves (2M x 4N), per-wave 128x64 = 4 mi x 2 nb 32x32 tiles (acc 128 VGPR).
// K-tile split in 4 k-steps of 16; per k-step: 6 ds_read_b128 (B 2 + A 4),
// 8 MFMA 32x32x16. Counted lgkm(6) pipelines read-groups against MFMA;
// staging (8 gld16) spread over P0-P2, vmcnt(0)+barrier once per tile.
// LDS layout (r6-verified 0-conflict): 128-B rows, byte ^= ((row&7)<<4).
// Frag addr: row = base + (lane&31), kbyte = (ks*32 + (lane>>5)*16) ^ swz.
// C/D map (m74/m101): col = lane&31, row = (reg&3) + 8*(reg>>2) + 4*(lane>>5).
template <int DO_GELU, int FUSE_COMBINE>
__global__ __launch_bounds__(512, 2) void gemm32_kernel(
    const unsigned short* __restrict__ A,   // [E][M][K] bf16
    const unsigned short* __restrict__ BT,  // [E][N][K] bf16
    unsigned short* __restrict__ Hout,      // [E][M][N] bf16 (GEMM1)
    const int* __restrict__ smap,           // [E][CAP] token map (GEMM2)
    const float* __restrict__ gate,         // [T]
    float* __restrict__ out,                // [T][D]
    int M, int N, int K) {
  __shared__ char lds[131072];  // [buf 64K][A 32K | B 32K], 256 rows x 128 B
  int tid = threadIdx.x, lane = tid & 63, w = tid >> 6;
  int wm = w >> 2, wn = w & 3;

  // bijective XCD-aware swizzle (nwg % 8 == 0)
  int gx = gridDim.x, gy = gridDim.y;
  long gid = blockIdx.x + (long)gx * (blockIdx.y + (long)gy * blockIdx.z);
  int nT = gx * gy * (int)gridDim.z;
  int cpx = nT >> 3;
  int swz = (int)((gid & 7) * (long)cpx + (gid >> 3));
  int bn = swz % gx;
  int bm = (swz / gx) % gy;
  int e  = swz / (gx * gy);

  const char* Ab = (const char*)(A + ((size_t)e * M + (size_t)bm * 256) * K);
  const char* Bb = (const char*)(BT + ((size_t)e * N + (size_t)bn * 256) * K);
  int K2 = K * 2;

  // staging source offsets: region phys p -> logical via involution
  unsigned sv[4];
#pragma unroll
  for (int q = 0; q < 4; ++q) {
    int p = q * 8192 + tid * 16;
    int lg = p ^ (((p >> 7) & 7) << 4);
    sv[q] = (unsigned)((lg >> 7) * K2 + (lg & 127));
  }
  char* dstB = (char*)lds + tid * 16;

  // fragment base addresses: one per k-step (swizzle folded), dbuf via ^65536
  unsigned lb = (unsigned)(size_t)(__attribute__((address_space(3))) char*)lds;
  int arow = wm * 128 + (lane & 31);
  int brow = wn * 64 + (lane & 31);
  unsigned kb = (unsigned)((lane >> 5) << 4);
  unsigned sA = (unsigned)((arow & 7) << 4), sB = (unsigned)((brow & 7) << 4);
  unsigned aK[4], bK[4];
#pragma unroll
  for (int ks = 0; ks < 4; ++ks) {
    aK[ks] = lb + (unsigned)(arow * 128) + ((ks * 32u + kb) ^ sA);
    bK[ks] = lb + 32768u + (unsigned)(brow * 128) + ((ks * 32u + kb) ^ sB);
  }

  f32x16 acc[4][2];
#pragma unroll
  for (int mi = 0; mi < 4; ++mi)
#pragma unroll
    for (int nb = 0; nb < 2; ++nb)
#pragma unroll
      for (int rr = 0; rr < 16; ++rr) acc[mi][nb][rr] = 0.f;

  bf16x8 ga[2][4], gb[2][2];
#define GRP(IX, KS) { \
    gb[IX][0] = dsr<0>(bK[KS]); gb[IX][1] = dsr<4096>(bK[KS]); \
    ga[IX][0] = dsr<0>(aK[KS]); ga[IX][1] = dsr<4096>(aK[KS]); \
    ga[IX][2] = dsr<8192>(aK[KS]); ga[IX][3] = dsr<12288>(aK[KS]); }
#define SB0 __builtin_amdgcn_sched_barrier(0)
#define CL8(IX) { \
    __builtin_amdgcn_s_setprio(1); \
    _Pragma("unroll") \
    for (int mi = 0; mi < 4; ++mi) { \
      acc[mi][0] = __builtin_amdgcn_mfma_f32_32x32x16_bf16(ga[IX][mi], gb[IX][0], acc[mi][0], 0, 0, 0); \
      acc[mi][1] = __builtin_amdgcn_mfma_f32_32x32x16_bf16(ga[IX][mi], gb[IX][1], acc[mi][1], 0, 0, 0); } \
    __builtin_amdgcn_s_setprio(0); }
#define BAR __builtin_amdgcn_s_barrier()

  int NT = K >> 6;
  // prologue: stage full tile 0 into buf0
#pragma unroll
  for (int q = 0; q < 4; ++q) {
    gld16(Ab + sv[q], dstB + q * 8192);
    gld16(Bb + sv[q], dstB + 32768 + q * 8192);
  }
  VMCNT(0);
  BAR;
  GRP(0, 0)

  for (int t = 0; t < NT; ++t) {
    bool pf = (t + 1 < NT);
    const char* An = Ab + (unsigned)(t + 1) * 128u;
    const char* Bn = Bb + (unsigned)(t + 1) * 128u;
    char* o = dstB + ((t & 1) ^ 1) * 65536;
    // P0: reads G1; stage B(t+1) x4; wait G0; MFMA ks0
    GRP(1, 1)
    if (pf) {
      gld16(Bn + sv[0], o + 32768); gld16(Bn + sv[1], o + 40960);
      gld16(Bn + sv[2], o + 49152); gld16(Bn + sv[3], o + 57344);
    }
    LGKM(6); SB0;
    CL8(0)
    // P1: reads G2; stage A-lo(t+1) x2; wait G1; MFMA ks1
    GRP(0, 2)
    if (pf) { gld16(An + sv[0], o); gld16(An + sv[1], o + 8192); }
    LGKM(6); SB0;
    CL8(1)
    // P2: reads G3; stage A-hi(t+1) x2; wait G2; MFMA ks2
    GRP(1, 3)
    if (pf) { gld16(An + sv[2], o + 16384); gld16(An + sv[3], o + 24576); }
    LGKM(6); SB0;
    CL8(0)
    // P3: wait G3; MFMA ks3; drain stage; barrier; swap; reads G0'
    LGKM(0); SB0;
    CL8(1)
    if (pf) {
      VMCNT(0);
      BAR;
#pragma unroll
      for (int ks = 0; ks < 4; ++ks) { aK[ks] ^= 65536u; bK[ks] ^= 65536u; }
      GRP(0, 0)
    }
  }
#undef GRP
#undef SB0
#undef CL8
#undef BAR

  // ---- epilogue (32x32 C/D layout) ----
  int r0 = bm * 256 + wm * 128;
  int c0 = bn * 256 + wn * 64 + (lane & 31);
  int rlh = (lane >> 5) << 2;
#pragma unroll
  for (int mi = 0; mi < 4; ++mi) {
#pragma unroll
    for (int rr = 0; rr < 16; ++rr) {
      int row = r0 + mi * 32 + (rr & 3) + ((rr >> 2) << 3) + rlh;
      if (DO_GELU) {
        size_t rb = ((size_t)e * M + row) * N + c0;
        Hout[rb]      = f2bf(gelu_tanh(acc[mi][0][rr]));
        Hout[rb + 32] = f2bf(gelu_tanh(acc[mi][1][rr]));
      }
      if (FUSE_COMBINE) {
        int tkn = smap[e * CAP + row];
        if (tkn >= 0) {
          float gt = gate[tkn];
          size_t ob = (size_t)tkn * Dd + c0;
          out[ob]      = acc[mi][0][rr] * gt;
          out[ob + 32] = acc[mi][1][rr] * gt;
        }
      }
    }
  }
}

extern "C" void kernel_launch(void* const* d_in, const int* in_sizes, int n_in,
                              void* d_out, int out_size, void* d_ws, size_t ws_size,
                              hipStream_t stream) {
  const float* x  = (const float*)d_in[0];
  const float* wg = (const float*)d_in[1];
  const float* w1 = (const float*)d_in[2];
  const float* w2 = (const float*)d_in[3];
  float* out = (float*)d_out;

  char* ws = (char*)d_ws;
  int*   idx  = (int*)(ws + 0);
  int*   pos  = (int*)(ws + 65536);
  float* gate = (float*)(ws + 131072);
  float* meP  = (float*)(ws + 196608);
  int*   smap = (int*)(ws + 327680);
  int*   cnt  = (int*)(ws + 393216);
  int*   base = (int*)(ws + 395264);
  unsigned short* Xg  = (unsigned short*)(ws + 401408ull);
  unsigned short* W1T = (unsigned short*)(ws + 33955840ull);
  unsigned short* W2T = (unsigned short*)(ws + 101064704ull);
  unsigned short* H   = (unsigned short*)(ws + 168173568ull);

  hipMemsetAsync(smap, 0xFF, Ee * CAP * 4, stream);
  gating_kernel<<<Tt / 4, 256, 0, stream>>>(x, wg, idx, gate, meP);
  count_kernel<<<Tt / 256, 256, 0, stream>>>(idx, cnt);
  prefix_kernel<<<1, 256, 0, stream>>>(cnt, base, meP, out + (size_t)Tt * Dd);
  assign_kernel<<<Tt / 256, 256, 0, stream>>>(idx, base, pos, smap);
  zero_dropped<<<256, 256, 0, stream>>>(pos, out);
  transpose_cast2<<<dim3(1024, 1, 16), 256, 0, stream>>>(w1, w2, W1T, W2T);
  build_xg<<<Ee * CAP, 256, 0, stream>>>(x, smap, Xg);
  gemm32_kernel<1, 0><<<dim3(DFFf / 256, CAP / 256, Ee), 512, 0, stream>>>(
      Xg, W1T, H, nullptr, nullptr, nullptr, CAP, DFFf, Dd);
  gemm32_kernel<0, 1><<<dim3(Dd / 256, CAP / 256, Ee), 512, 0, stream>>>(
      H, W2T, nullptr, smap, gate, out, CAP, Dd, DFFf);
}

// Round 12
// 476.313 us; speedup vs baseline: 1.0949x; 1.0949x over previous
//
#include <hip/hip_runtime.h>
#include <hip/hip_bf16.h>

#define Tt   16384
#define Dd   1024
#define Ee   8
#define CAP  2048
#define DFFf 4096

typedef __attribute__((ext_vector_type(8))) short bf16x8;
typedef __attribute__((ext_vector_type(4))) float f32x4;

__device__ __forceinline__ unsigned short f2bf(float f) {
  union { float f; unsigned u; } v; v.f = f;
  unsigned r = (v.u + 0x7FFFu + ((v.u >> 16) & 1u)) >> 16;
  return (unsigned short)r;
}

__device__ __forceinline__ float gelu_tanh(float x) {
  float z = 0.7978845608028654f * (x + 0.044715f * x * x * x);
  float az = fabsf(z);
  float t = __expf(-2.0f * az);
  float th = (1.0f - t) / (1.0f + t);
  th = (z < 0.0f) ? -th : th;
  return 0.5f * x * (1.0f + th);
}

__device__ __forceinline__ void gld16(const void* g, void* l) {
  __builtin_amdgcn_global_load_lds(
      (const __attribute__((address_space(1))) void*)g,
      (__attribute__((address_space(3))) void*)l,
      16, 0, 0);
}

template <int IMM>
__device__ __forceinline__ bf16x8 dsr(unsigned a) {
  bf16x8 r;
  asm volatile("ds_read_b128 %0, %1 offset:%c2" : "=v"(r) : "v"(a), "i"(IMM));
  return r;
}
#define LGKM(N) asm volatile("s_waitcnt lgkmcnt(" #N ")" ::: "memory")
#define VMCNT(N) asm volatile("s_waitcnt vmcnt(" #N ")" ::: "memory")

// ---------------- gating: logits fp32, softmax, argmax ----------------
__global__ __launch_bounds__(256) void gating_kernel(
    const float* __restrict__ x, const float* __restrict__ wg,
    int* __restrict__ idx, float* __restrict__ gate, float* __restrict__ meP) {
  int tid = threadIdx.x, lane = tid & 63, w = tid >> 6;
  int t = blockIdx.x * 4 + w;
  const float* xr = x + (size_t)t * Dd;
  float p[8];
#pragma unroll
  for (int e2 = 0; e2 < 8; ++e2) p[e2] = 0.f;
#pragma unroll
  for (int i = 0; i < 16; ++i) {
    int j = lane + (i << 6);
    float xv = xr[j];
    const float4* wr = (const float4*)(wg + j * 8);
    float4 a = wr[0], b = wr[1];
    p[0] += xv * a.x; p[1] += xv * a.y; p[2] += xv * a.z; p[3] += xv * a.w;
    p[4] += xv * b.x; p[5] += xv * b.y; p[6] += xv * b.z; p[7] += xv * b.w;
  }
#pragma unroll
  for (int off = 32; off > 0; off >>= 1)
#pragma unroll
    for (int e2 = 0; e2 < 8; ++e2) p[e2] += __shfl_xor(p[e2], off);
  __shared__ float smG[4][8];
  if (lane == 0) {
    float mx = p[0]; int am = 0;
#pragma unroll
    for (int e2 = 1; e2 < 8; ++e2) if (p[e2] > mx) { mx = p[e2]; am = e2; }
    float s = 0.f, g2[8];
#pragma unroll
    for (int e2 = 0; e2 < 8; ++e2) { g2[e2] = __expf(p[e2] - mx); s += g2[e2]; }
    float inv = 1.f / s;
    idx[t] = am;
    gate[t] = g2[am] * inv;
#pragma unroll
    for (int e2 = 0; e2 < 8; ++e2) smG[w][e2] = g2[e2] * inv;
  }
  __syncthreads();
  if (tid < 8)
    meP[blockIdx.x * 8 + tid] = smG[0][tid] + smG[1][tid] + smG[2][tid] + smG[3][tid];
}

// ------------- parallel scan, stage 1: per-chunk expert counts -------------
__global__ __launch_bounds__(256) void count_kernel(
    const int* __restrict__ idx, int* __restrict__ cnt) {
  int tid = threadIdx.x, lane = tid & 63, w = tid >> 6;
  int e = idx[blockIdx.x * 256 + tid];
  __shared__ int c[4][8];
#pragma unroll
  for (int q = 0; q < 8; ++q) {
    unsigned long long m = __ballot(e == q);
    if (lane == 0) c[w][q] = (int)__popcll(m);
  }
  __syncthreads();
  if (tid < 8)
    cnt[blockIdx.x * 8 + tid] = c[0][tid] + c[1][tid] + c[2][tid] + c[3][tid];
}

// ------------- stage 2: exclusive prefix over chunks + l_aux -------------
__global__ __launch_bounds__(256) void prefix_kernel(
    const int* __restrict__ cnt, int* __restrict__ base,
    const float* __restrict__ meP, float* __restrict__ laux_out) {
  int tid = threadIdx.x;
  __shared__ int tot[8];
  __shared__ float red[256];
  __shared__ float smes[8];
  if (tid < 8) {
    int run = 0;
    for (int b2 = 0; b2 < 64; ++b2) { base[b2 * 8 + tid] = run; run += cnt[b2 * 8 + tid]; }
    tot[tid] = run;
  }
  float part = 0.f;
  int e2 = tid & 7, r0 = tid >> 3;
  for (int b2 = r0; b2 < 4096; b2 += 32) part += meP[b2 * 8 + e2];
  red[tid] = part;
  __syncthreads();
  if (tid < 8) {
    float s = 0.f;
    for (int i = 0; i < 32; ++i) s += red[i * 8 + tid];
    smes[tid] = s * (float)tot[tid];
  }
  __syncthreads();
  if (tid == 0) {
    float l = 0.f;
    for (int q = 0; q < 8; ++q) l += smes[q];
    laux_out[0] = l * 8.0f / ((float)Tt * (float)Tt);
  }
}

// ------------- stage 3: assign positions + slot map -------------
__global__ __launch_bounds__(256) void assign_kernel(
    const int* __restrict__ idx, const int* __restrict__ base,
    int* __restrict__ pos, int* __restrict__ smap) {
  int tid = threadIdx.x, lane = tid & 63, w = tid >> 6;
  int t = blockIdx.x * 256 + tid;
  int e = idx[t];
  __shared__ int wc[4][8];
  int myoff = 0;
#pragma unroll
  for (int q = 0; q < 8; ++q) {
    unsigned long long m = __ballot(e == q);
    if (lane == 0) wc[w][q] = (int)__popcll(m);
    if (e == q) myoff = (int)__popcll(m & ((1ull << lane) - 1ull));
  }
  __syncthreads();
  int b = base[blockIdx.x * 8 + e];
  for (int ww = 0; ww < w; ++ww) b += wc[ww][e];
  int p = b + myoff;
  pos[t] = p;
  if (p < CAP) smap[e * CAP + p] = t;
}

// ------------- zero dropped-token output rows (grid-stride) -------------
__global__ __launch_bounds__(256) void zero_dropped(
    const int* __restrict__ pos, float* __restrict__ out) {
  for (int t = blockIdx.x; t < Tt; t += gridDim.x) {
    if (pos[t] < CAP) continue;
    ((float4*)(out + (size_t)t * Dd))[threadIdx.x] = make_float4(0.f, 0.f, 0.f, 0.f);
  }
}

// ---- merged transpose + cast fp32 -> bf16, VECTORIZED ushort4 stores -------
// dst[c][r] = bf16(src[r][c]). 64x64 tile; stores: 16 lanes x ushort4 = one
// 128-B dst row segment (full coalescing); LDS read banks (4i+c)%32 -> 2-way max.
__global__ __launch_bounds__(256) void transpose_cast2(
    const float* __restrict__ w1, const float* __restrict__ w2,
    unsigned short* __restrict__ W1T, unsigned short* __restrict__ W2T) {
  __shared__ float tile[64][65];
  int z = blockIdx.z, tz = blockIdx.x;
  const float* s; unsigned short* d; int R, Cn, rb, cb;
  if (z < 8) {
    s = w1 + (size_t)z * Dd * DFFf; d = W1T + (size_t)z * Dd * DFFf;
    R = Dd; Cn = DFFf; rb = (tz >> 6) * 64; cb = (tz & 63) * 64;
  } else {
    s = w2 + (size_t)(z - 8) * DFFf * Dd; d = W2T + (size_t)(z - 8) * DFFf * Dd;
    R = DFFf; Cn = Dd; rb = (tz >> 4) * 64; cb = (tz & 15) * 64;
  }
  int tid = threadIdx.x;
  int c = tid & 63;
  int r0 = tid >> 6;
#pragma unroll
  for (int i = 0; i < 16; ++i) {
    int r = r0 + i * 4;
    tile[r][c] = s[(size_t)(rb + r) * Cn + cb + c];
  }
  __syncthreads();
  int cc0 = (tid & 15) * 4;
  int rr0 = tid >> 4;   // 16 rows per pass, 4 passes
#pragma unroll
  for (int p = 0; p < 4; ++p) {
    int rr = rr0 + p * 16;
    ushort4 o;
    o.x = f2bf(tile[cc0 + 0][rr]);
    o.y = f2bf(tile[cc0 + 1][rr]);
    o.z = f2bf(tile[cc0 + 2][rr]);
    o.w = f2bf(tile[cc0 + 3][rr]);
    *(ushort4*)(d + (size_t)(cb + rr) * R + rb + cc0) = o;
  }
}

// ------------- gather + cast dispatched tokens -------------
__global__ __launch_bounds__(256) void build_xg(
    const float* __restrict__ x, const int* __restrict__ smap,
    unsigned short* __restrict__ Xg) {
  int row = blockIdx.x;
  int t = smap[row];
  int j = threadIdx.x;
  float4 v = make_float4(0.f, 0.f, 0.f, 0.f);
  if (t >= 0) v = ((const float4*)(x + (size_t)t * Dd))[j];
  ushort4 o;
  o.x = f2bf(v.x); o.y = f2bf(v.y); o.z = f2bf(v.z); o.w = f2bf(v.w);
  ((ushort4*)(Xg + (size_t)row * Dd))[j] = o;
}

// ------------- 256^2-tile bf16 MFMA GEMM (B^T), counted-vmcnt dbuf (r6) -----
// 8 waves (2M x 4N), per-wave 128x64, BK=64, dbuf LDS, 0-conflict XOR layout.
// Staging split P0/P1/P2; waits vmcnt(4)@P1 (3-phase cover), vmcnt(2)@P3;
// never 0 in steady loop. ds_read groups pipelined with counted lgkm 8/4/4/0.
template <int DO_GELU, int FUSE_COMBINE>
__global__ __launch_bounds__(512, 2) void gemm256_kernel(
    const unsigned short* __restrict__ A,   // [E][M][K] bf16
    const unsigned short* __restrict__ BT,  // [E][N][K] bf16
    unsigned short* __restrict__ Hout,      // [E][M][N] bf16 (GEMM1)
    const int* __restrict__ smap,           // [E][CAP] token map (GEMM2)
    const float* __restrict__ gate,         // [T]
    float* __restrict__ out,                // [T][D]
    int M, int N, int K) {
  __shared__ unsigned short lds[2][2][16384];  // [buf][A/B][256 rows x 64 k]
  int tid = threadIdx.x, lane = tid & 63, w = tid >> 6;
  int wm = w >> 2, wn = w & 3;

  // bijective XCD-aware swizzle (nwg % 8 == 0)
  int gx = gridDim.x, gy = gridDim.y;
  long gid = blockIdx.x + (long)gx * (blockIdx.y + (long)gy * blockIdx.z);
  int nT = gx * gy * (int)gridDim.z;
  int cpx = nT >> 3;
  int swz = (int)((gid & 7) * (long)cpx + (gid >> 3));
  int bn = swz % gx;
  int bm = (swz / gx) % gy;
  int e  = swz / (gx * gy);

  const unsigned short* Ab = A + ((size_t)e * M + (size_t)bm * 256) * K;
  const unsigned short* Bb = BT + ((size_t)e * N + (size_t)bn * 256) * K;

  // phys p holds logical p ^ (((p>>7)&7)<<4) (involution, both-sides swizzle)
  auto stageB = [&](const unsigned short* src, unsigned short* L, int h) {
#pragma unroll
    for (int q = 0; q < 2; ++q) {
      int p = h * 16384 + q * 8192 + tid * 16;
      int lg = p ^ (((p >> 7) & 7) << 4);
      gld16(src + (size_t)(lg >> 7) * K + ((lg & 127) >> 1),
            (unsigned short*)((char*)L + p));
    }
  };
  auto stageA = [&](const unsigned short* src, unsigned short* L, int h) {
#pragma unroll
    for (int q = 0; q < 2; ++q) {
      int p = q * 16384 + h * 8192 + tid * 16;
      int lg = p ^ (((p >> 7) & 7) << 4);
      gld16(src + (size_t)(lg >> 7) * K + ((lg & 127) >> 1),
            (unsigned short*)((char*)L + p));
    }
  };

  f32x4 acc[2][4][4];
#pragma unroll
  for (int mh = 0; mh < 2; ++mh)
#pragma unroll
    for (int mi = 0; mi < 4; ++mi)
#pragma unroll
      for (int n = 0; n < 4; ++n) acc[mh][mi][n] = (f32x4){0.f, 0.f, 0.f, 0.f};

  auto mfma16 = [&](f32x4 (*ac)[4], const bf16x8* av, const bf16x8* bv) {
#pragma unroll
    for (int mi = 0; mi < 4; ++mi)
#pragma unroll
      for (int n = 0; n < 4; ++n)
        ac[mi][n] = __builtin_amdgcn_mfma_f32_16x16x32_bf16(av[mi], bv[n], ac[mi][n], 0, 0, 0);
  };

  unsigned lbase = (unsigned)(size_t)(__attribute__((address_space(3))) unsigned short*)&lds[0][0][0];
  int arow = wm * 128 + (lane & 15);
  int brow = wn * 64 + (lane & 15);
  unsigned kc2 = (unsigned)(((lane >> 4) << 3) << 1);
  unsigned swA = (unsigned)((arow & 7) << 4), swB = (unsigned)((brow & 7) << 4);
  unsigned ak0 = lbase + ((((unsigned)arow << 7) + kc2) ^ swA);
  unsigned ak1 = lbase + ((((unsigned)arow << 7) + 64 + kc2) ^ swA);
  unsigned bk0 = lbase + 32768u + ((((unsigned)brow << 7) + kc2) ^ swB);
  unsigned bk1 = lbase + 32768u + ((((unsigned)brow << 7) + 64 + kc2) ^ swB);

  bf16x8 a0[4], a1[4], a2[4], a3[4], b0[4], b1[4];
#define G0_ { \
    b0[0] = dsr<0>(bk0); b0[1] = dsr<2048>(bk0); b0[2] = dsr<4096>(bk0); b0[3] = dsr<6144>(bk0); \
    a0[0] = dsr<0>(ak0); a0[1] = dsr<2048>(ak0); a0[2] = dsr<4096>(ak0); a0[3] = dsr<6144>(ak0); }
#define G1_ { \
    b1[0] = dsr<0>(bk1); b1[1] = dsr<2048>(bk1); b1[2] = dsr<4096>(bk1); b1[3] = dsr<6144>(bk1); \
    a1[0] = dsr<0>(ak1); a1[1] = dsr<2048>(ak1); a1[2] = dsr<4096>(ak1); a1[3] = dsr<6144>(ak1); }
#define G2_ { \
    a2[0] = dsr<8192>(ak0); a2[1] = dsr<10240>(ak0); a2[2] = dsr<12288>(ak0); a2[3] = dsr<14336>(ak0); }
#define G3_ { \
    a3[0] = dsr<8192>(ak1); a3[1] = dsr<10240>(ak1); a3[2] = dsr<12288>(ak1); a3[3] = dsr<14336>(ak1); }
#define SB0 __builtin_amdgcn_sched_barrier(0)
#define PRIO_MFMA(AC, AV, BV) { \
    __builtin_amdgcn_s_setprio(1); mfma16(AC, AV, BV); __builtin_amdgcn_s_setprio(0); }

  int NT = K >> 6;
  stageB(Bb, lds[0][1], 0); stageB(Bb, lds[0][1], 1);
  stageA(Ab, lds[0][0], 0);
  stageA(Ab, lds[0][0], 1);
  VMCNT(2);
  __builtin_amdgcn_s_barrier();
  G0_

  for (int t = 0; t < NT - 1; ++t) {
    unsigned short* SA = lds[(t & 1) ^ 1][0];
    unsigned short* SB = lds[(t & 1) ^ 1][1];
    const unsigned short* An = Ab + ((t + 1) << 6);
    const unsigned short* Bn = Bb + ((t + 1) << 6);
    // ---- P0: reads G1; stage B(t+1); wait G0; MFMA a0xb0 ----
    G1_
    stageB(Bn, SB, 0); stageB(Bn, SB, 1);
    LGKM(8); SB0;
    PRIO_MFMA(acc[0], a0, b0);
    // ---- P1: drain A-h1(t); reads G2; stage A-h0(t+1); wait G1; MFMA a1xb1 ----
    VMCNT(4);
    __builtin_amdgcn_s_barrier();
    G2_
    stageA(An, SA, 0);
    LGKM(4); SB0;
    PRIO_MFMA(acc[0], a1, b1);
    // ---- P2: reads G3; stage A-h1(t+1); wait G2; MFMA a2xb0 ----
    G3_
    stageA(An, SA, 1);
    LGKM(4); SB0;
    PRIO_MFMA(acc[1], a2, b0);
    // ---- P3: wait G3; MFMA a3xb1; drain B+A-h0(t+1); swap; reads G0 ----
    LGKM(0); SB0;
    PRIO_MFMA(acc[1], a3, b1);
    VMCNT(2);
    __builtin_amdgcn_s_barrier();
    ak0 ^= 65536u; ak1 ^= 65536u; bk0 ^= 65536u; bk1 ^= 65536u;
    G0_
  }

  // ---- final tile: no staging; single vmcnt(0) at P1 ----
  G1_
  LGKM(8); SB0;
  PRIO_MFMA(acc[0], a0, b0);
  VMCNT(0);
  __builtin_amdgcn_s_barrier();
  G2_
  LGKM(4); SB0;
  PRIO_MFMA(acc[0], a1, b1);
  G3_
  LGKM(4); SB0;
  PRIO_MFMA(acc[1], a2, b0);
  LGKM(0); SB0;
  PRIO_MFMA(acc[1], a3, b1);

#undef G0_
#undef G1_
#undef G2_
#undef G3_
#undef SB0
#undef PRIO_MFMA

  // ---- epilogue ----
  int r0 = bm * 256 + wm * 128;
  int c0 = bn * 256 + wn * 64;
#pragma unroll
  for (int mh = 0; mh < 2; ++mh)
#pragma unroll
    for (int mi = 0; mi < 4; ++mi) {
      int rowb = r0 + mh * 64 + mi * 16 + ((lane >> 4) << 2);
#pragma unroll
      for (int r = 0; r < 4; ++r) {
        int row = rowb + r;
        if (DO_GELU) {
#pragma unroll
          for (int n = 0; n < 4; ++n) {
            int col = c0 + n * 16 + (lane & 15);
            Hout[((size_t)e * M + row) * N + col] = f2bf(gelu_tanh(acc[mh][mi][n][r]));
          }
        }
        if (FUSE_COMBINE) {
          int tkn = smap[e * CAP + row];
          if (tkn >= 0) {
            float g = gate[tkn];
#pragma unroll
            for (int n = 0; n < 4; ++n) {
              int col = c0 + n * 16 + (lane & 15);
              out[(size_t)tkn * Dd + col] = acc[mh][mi][n][r] * g;
            }
          }
        }
      }
    }
}

extern "C" void kernel_launch(void* const* d_in, const int* in_sizes, int n_in,
                              void* d_out, int out_size, void* d_ws, size_t ws_size,
                              hipStream_t stream) {
  const float* x  = (const float*)d_in[0];
  const float* wg = (const float*)d_in[1];
  const float* w1 = (const float*)d_in[2];
  const float* w2 = (const float*)d_in[3];
  float* out = (float*)d_out;

  char* ws = (char*)d_ws;
  int*   idx  = (int*)(ws + 0);
  int*   pos  = (int*)(ws + 65536);
  float* gate = (float*)(ws + 131072);
  float* meP  = (float*)(ws + 196608);
  int*   smap = (int*)(ws + 327680);
  int*   cnt  = (int*)(ws + 393216);
  int*   base = (int*)(ws + 395264);
  unsigned short* Xg  = (unsigned short*)(ws + 401408ull);
  unsigned short* W1T = (unsigned short*)(ws + 33955840ull);
  unsigned short* W2T = (unsigned short*)(ws + 101064704ull);
  unsigned short* H   = (unsigned short*)(ws + 168173568ull);

  hipMemsetAsync(smap, 0xFF, Ee * CAP * 4, stream);
  gating_kernel<<<Tt / 4, 256, 0, stream>>>(x, wg, idx, gate, meP);
  count_kernel<<<Tt / 256, 256, 0, stream>>>(idx, cnt);
  prefix_kernel<<<1, 256, 0, stream>>>(cnt, base, meP, out + (size_t)Tt * Dd);
  assign_kernel<<<Tt / 256, 256, 0, stream>>>(idx, base, pos, smap);
  zero_dropped<<<256, 256, 0, stream>>>(pos, out);
  transpose_cast2<<<dim3(1024, 1, 16), 256, 0, stream>>>(w1, w2, W1T, W2T);
  build_xg<<<Ee * CAP, 256, 0, stream>>>(x, smap, Xg);
  gemm256_kernel<1, 0><<<dim3(DFFf / 256, CAP / 256, Ee), 512, 0, stream>>>(
      Xg, W1T, H, nullptr, nullptr, nullptr, CAP, DFFf, Dd);
  gemm256_kernel<0, 1><<<dim3(Dd / 256, CAP / 256, Ee), 512, 0, stream>>>(
      H, W2T, nullptr, smap, gate, out, CAP, Dd, DFFf);
}

// Round 13
// 474.580 us; speedup vs baseline: 1.0989x; 1.0037x over previous
//
#include <hip/hip_runtime.h>
#include <hip/hip_bf16.h>

#define Tt   16384
#define Dd   1024
#define Ee   8
#define CAP  2048
#define DFFf 4096

typedef __attribute__((ext_vector_type(8))) short bf16x8;
typedef __attribute__((ext_vector_type(4))) float f32x4;

__device__ __forceinline__ unsigned short f2bf(float f) {
  union { float f; unsigned u; } v; v.f = f;
  unsigned r = (v.u + 0x7FFFu + ((v.u >> 16) & 1u)) >> 16;
  return (unsigned short)r;
}

__device__ __forceinline__ float gelu_tanh(float x) {
  float z = 0.7978845608028654f * (x + 0.044715f * x * x * x);
  float az = fabsf(z);
  float t = __expf(-2.0f * az);
  float th = (1.0f - t) / (1.0f + t);
  th = (z < 0.0f) ? -th : th;
  return 0.5f * x * (1.0f + th);
}

__device__ __forceinline__ void gld16(const void* g, void* l) {
  __builtin_amdgcn_global_load_lds(
      (const __attribute__((address_space(1))) void*)g,
      (__attribute__((address_space(3))) void*)l,
      16, 0, 0);
}

template <int IMM>
__device__ __forceinline__ bf16x8 dsr(unsigned a) {
  bf16x8 r;
  asm volatile("ds_read_b128 %0, %1 offset:%c2" : "=v"(r) : "v"(a), "i"(IMM));
  return r;
}
#define LGKM(N) asm volatile("s_waitcnt lgkmcnt(" #N ")" ::: "memory")
#define VMCNT(N) asm volatile("s_waitcnt vmcnt(" #N ")" ::: "memory")

// ---------------- gating: logits fp32, softmax, argmax ----------------
__global__ __launch_bounds__(256) void gating_kernel(
    const float* __restrict__ x, const float* __restrict__ wg,
    int* __restrict__ idx, float* __restrict__ gate, float* __restrict__ meP) {
  int tid = threadIdx.x, lane = tid & 63, w = tid >> 6;
  int t = blockIdx.x * 4 + w;
  const float* xr = x + (size_t)t * Dd;
  float p[8];
#pragma unroll
  for (int e2 = 0; e2 < 8; ++e2) p[e2] = 0.f;
#pragma unroll
  for (int i = 0; i < 16; ++i) {
    int j = lane + (i << 6);
    float xv = xr[j];
    const float4* wr = (const float4*)(wg + j * 8);
    float4 a = wr[0], b = wr[1];
    p[0] += xv * a.x; p[1] += xv * a.y; p[2] += xv * a.z; p[3] += xv * a.w;
    p[4] += xv * b.x; p[5] += xv * b.y; p[6] += xv * b.z; p[7] += xv * b.w;
  }
#pragma unroll
  for (int off = 32; off > 0; off >>= 1)
#pragma unroll
    for (int e2 = 0; e2 < 8; ++e2) p[e2] += __shfl_xor(p[e2], off);
  __shared__ float smG[4][8];
  if (lane == 0) {
    float mx = p[0]; int am = 0;
#pragma unroll
    for (int e2 = 1; e2 < 8; ++e2) if (p[e2] > mx) { mx = p[e2]; am = e2; }
    float s = 0.f, g2[8];
#pragma unroll
    for (int e2 = 0; e2 < 8; ++e2) { g2[e2] = __expf(p[e2] - mx); s += g2[e2]; }
    float inv = 1.f / s;
    idx[t] = am;
    gate[t] = g2[am] * inv;
#pragma unroll
    for (int e2 = 0; e2 < 8; ++e2) smG[w][e2] = g2[e2] * inv;
  }
  __syncthreads();
  if (tid < 8)
    meP[blockIdx.x * 8 + tid] = smG[0][tid] + smG[1][tid] + smG[2][tid] + smG[3][tid];
}

// ------------- parallel scan, stage 1: per-chunk expert counts -------------
__global__ __launch_bounds__(256) void count_kernel(
    const int* __restrict__ idx, int* __restrict__ cnt) {
  int tid = threadIdx.x, lane = tid & 63, w = tid >> 6;
  int e = idx[blockIdx.x * 256 + tid];
  __shared__ int c[4][8];
#pragma unroll
  for (int q = 0; q < 8; ++q) {
    unsigned long long m = __ballot(e == q);
    if (lane == 0) c[w][q] = (int)__popcll(m);
  }
  __syncthreads();
  if (tid < 8)
    cnt[blockIdx.x * 8 + tid] = c[0][tid] + c[1][tid] + c[2][tid] + c[3][tid];
}

// ------------- stage 2: exclusive prefix over chunks + l_aux -------------
__global__ __launch_bounds__(256) void prefix_kernel(
    const int* __restrict__ cnt, int* __restrict__ base,
    const float* __restrict__ meP, float* __restrict__ laux_out) {
  int tid = threadIdx.x;
  __shared__ int tot[8];
  __shared__ float red[256];
  __shared__ float smes[8];
  if (tid < 8) {
    int run = 0;
    for (int b2 = 0; b2 < 64; ++b2) { base[b2 * 8 + tid] = run; run += cnt[b2 * 8 + tid]; }
    tot[tid] = run;
  }
  float part = 0.f;
  int e2 = tid & 7, r0 = tid >> 3;
  for (int b2 = r0; b2 < 4096; b2 += 32) part += meP[b2 * 8 + e2];
  red[tid] = part;
  __syncthreads();
  if (tid < 8) {
    float s = 0.f;
    for (int i = 0; i < 32; ++i) s += red[i * 8 + tid];
    smes[tid] = s * (float)tot[tid];
  }
  __syncthreads();
  if (tid == 0) {
    float l = 0.f;
    for (int q = 0; q < 8; ++q) l += smes[q];
    laux_out[0] = l * 8.0f / ((float)Tt * (float)Tt);
  }
}

// ------------- stage 3: assign positions + slot map -------------
__global__ __launch_bounds__(256) void assign_kernel(
    const int* __restrict__ idx, const int* __restrict__ base,
    int* __restrict__ pos, int* __restrict__ smap) {
  int tid = threadIdx.x, lane = tid & 63, w = tid >> 6;
  int t = blockIdx.x * 256 + tid;
  int e = idx[t];
  __shared__ int wc[4][8];
  int myoff = 0;
#pragma unroll
  for (int q = 0; q < 8; ++q) {
    unsigned long long m = __ballot(e == q);
    if (lane == 0) wc[w][q] = (int)__popcll(m);
    if (e == q) myoff = (int)__popcll(m & ((1ull << lane) - 1ull));
  }
  __syncthreads();
  int b = base[blockIdx.x * 8 + e];
  for (int ww = 0; ww < w; ++ww) b += wc[ww][e];
  int p = b + myoff;
  pos[t] = p;
  if (p < CAP) smap[e * CAP + p] = t;
}

// ------------- zero dropped-token output rows (grid-stride) -------------
__global__ __launch_bounds__(256) void zero_dropped(
    const int* __restrict__ pos, float* __restrict__ out) {
  for (int t = blockIdx.x; t < Tt; t += gridDim.x) {
    if (pos[t] < CAP) continue;
    ((float4*)(out + (size_t)t * Dd))[threadIdx.x] = make_float4(0.f, 0.f, 0.f, 0.f);
  }
}

// ---- merged transpose + cast fp32 -> bf16, vectorized ushort4 stores -------
__global__ __launch_bounds__(256) void transpose_cast2(
    const float* __restrict__ w1, const float* __restrict__ w2,
    unsigned short* __restrict__ W1T, unsigned short* __restrict__ W2T) {
  __shared__ float tile[64][65];
  int z = blockIdx.z, tz = blockIdx.x;
  const float* s; unsigned short* d; int R, Cn, rb, cb;
  if (z < 8) {
    s = w1 + (size_t)z * Dd * DFFf; d = W1T + (size_t)z * Dd * DFFf;
    R = Dd; Cn = DFFf; rb = (tz >> 6) * 64; cb = (tz & 63) * 64;
  } else {
    s = w2 + (size_t)(z - 8) * DFFf * Dd; d = W2T + (size_t)(z - 8) * DFFf * Dd;
    R = DFFf; Cn = Dd; rb = (tz >> 4) * 64; cb = (tz & 15) * 64;
  }
  int tid = threadIdx.x;
  int c = tid & 63;
  int r0 = tid >> 6;
#pragma unroll
  for (int i = 0; i < 16; ++i) {
    int r = r0 + i * 4;
    tile[r][c] = s[(size_t)(rb + r) * Cn + cb + c];
  }
  __syncthreads();
  int cc0 = (tid & 15) * 4;
  int rr0 = tid >> 4;
#pragma unroll
  for (int p = 0; p < 4; ++p) {
    int rr = rr0 + p * 16;
    ushort4 o;
    o.x = f2bf(tile[cc0 + 0][rr]);
    o.y = f2bf(tile[cc0 + 1][rr]);
    o.z = f2bf(tile[cc0 + 2][rr]);
    o.w = f2bf(tile[cc0 + 3][rr]);
    *(ushort4*)(d + (size_t)(cb + rr) * R + rb + cc0) = o;
  }
}

// ------------- gather + cast dispatched tokens -------------
__global__ __launch_bounds__(256) void build_xg(
    const float* __restrict__ x, const int* __restrict__ smap,
    unsigned short* __restrict__ Xg) {
  int row = blockIdx.x;
  int t = smap[row];
  int j = threadIdx.x;
  float4 v = make_float4(0.f, 0.f, 0.f, 0.f);
  if (t >= 0) v = ((const float4*)(x + (size_t)t * Dd))[j];
  ushort4 o;
  o.x = f2bf(v.x); o.y = f2bf(v.y); o.z = f2bf(v.z); o.w = f2bf(v.w);
  ((ushort4*)(Xg + (size_t)row * Dd))[j] = o;
}

// ---- 256^2-tile bf16 MFMA GEMM (B^T), m201 8-phase/2-K-tile schedule -------
// 8 waves (2M x 4N), per-wave 128x64. Phases = C-quadrants x full K=64, order
// (mh0,nh0),(mh0,nh1),(mh1,nh1),(mh1,nh0); B frags held 4 phases, A per-half.
// LDS 128K: A [0,64K) = buf{0,1} x mh{0,1} 16K half-regions; B +64K with nh.
// Slot packing: A slot = mh*128+wm*64+r; B slot = nh*128+wn*32+r (contiguous
// half-regions; r6 0-conflict XOR layout preserved). Stage = 1 half (2 gld16)
// per phase: ph1 A-mh1(t1->buf1), ph2-5 tile t2->buf0 {A-mh0,B-a,B-b,A-mh1},
// ph6-8 tile t3->buf1 {A-mh0,B-a,B-b}. vmcnt(6) ONLY at ph4/ph8 (3 halves in
// flight; drains 3-6-phase-old loads; never 0 until peeled last iteration).
template <int DO_GELU, int FUSE_COMBINE>
__global__ __launch_bounds__(512, 2) void gemm8p_kernel(
    const unsigned short* __restrict__ A,   // [E][M][K] bf16
    const unsigned short* __restrict__ BT,  // [E][N][K] bf16
    unsigned short* __restrict__ Hout,      // [E][M][N] bf16 (GEMM1)
    const int* __restrict__ smap,           // [E][CAP] token map (GEMM2)
    const float* __restrict__ gate,         // [T]
    float* __restrict__ out,                // [T][D]
    int M, int N, int K) {
  __shared__ char lds[131072];
  int tid = threadIdx.x, lane = tid & 63, w = tid >> 6;
  int wm = w >> 2, wn = w & 3;

  // bijective XCD-aware swizzle (nwg % 8 == 0)
  int gx = gridDim.x, gy = gridDim.y;
  long gid = blockIdx.x + (long)gx * (blockIdx.y + (long)gy * blockIdx.z);
  int nT = gx * gy * (int)gridDim.z;
  int cpx = nT >> 3;
  int swz = (int)((gid & 7) * (long)cpx + (gid >> 3));
  int bn = swz % gx;
  int bm = (swz / gx) % gy;
  int e  = swz / (gx * gy);

  const char* Asrc = (const char*)(A + ((size_t)e * M + (size_t)bm * 256) * K);
  const char* Bsrc = (const char*)(BT + ((size_t)e * N + (size_t)bn * 256) * K);
  int K2 = K * 2;

  // stage source offsets per region [h][q]; phys p in 16K half-region:
  // lg = p^swz; line l = lg>>7 (local slot), col = lg&127; global row from slot.
  unsigned oA[2][2], oB[2][2];
#pragma unroll
  for (int q = 0; q < 2; ++q) {
    int p = q * 8192 + tid * 16;
    int lg = p ^ (((p >> 7) & 7) << 4);
    int l = lg >> 7, col = lg & 127;
    oA[0][q] = (unsigned)(((l >> 6) * 128 + (l & 63)) * K2 + col);
    oA[1][q] = (unsigned)(((l >> 6) * 128 + 64 + (l & 63)) * K2 + col);
    oB[0][q] = (unsigned)(((l >> 5) * 64 + (l & 31)) * K2 + col);
    oB[1][q] = (unsigned)(((l >> 5) * 64 + 32 + (l & 31)) * K2 + col);
  }
  char* dA = (char*)lds + tid * 16;
  char* dB = (char*)lds + 65536 + tid * 16;

  // STG(OP, H, TILE, BUFB): stage one half-region (2 gld16)
#define STG_A(H, TILE, BUFB) { \
    const char* s_ = Asrc + (unsigned)(TILE) * 128u; \
    char* d_ = dA + (BUFB) * 32768 + (H) * 16384; \
    gld16(s_ + oA[H][0], d_); gld16(s_ + oA[H][1], d_ + 8192); }
#define STG_B(H, TILE, BUFB) { \
    const char* s_ = Bsrc + (unsigned)(TILE) * 128u; \
    char* d_ = dB + (BUFB) * 32768 + (H) * 16384; \
    gld16(s_ + oB[H][0], d_); gld16(s_ + oB[H][1], d_ + 8192); }

  // fragment bases (ks0/ks1); frag addr = base + imm(buf*32768 + h*16384 + f*2048)
  unsigned lb = (unsigned)(size_t)(__attribute__((address_space(3))) char*)lds;
  unsigned msk = (unsigned)((lane & 7) << 4);
  unsigned kt = (unsigned)((lane >> 4) << 4);
  unsigned aB0 = lb + (unsigned)(wm * 8192 + (lane & 15) * 128) + (kt ^ msk);
  unsigned aB1 = lb + (unsigned)(wm * 8192 + (lane & 15) * 128) + ((kt + 64) ^ msk);
  unsigned bB0 = lb + 65536u + (unsigned)(wn * 4096 + (lane & 15) * 128) + (kt ^ msk);
  unsigned bB1 = lb + 65536u + (unsigned)(wn * 4096 + (lane & 15) * 128) + ((kt + 64) ^ msk);

  f32x4 acc[2][4][4];
#pragma unroll
  for (int mh = 0; mh < 2; ++mh)
#pragma unroll
    for (int mi = 0; mi < 4; ++mi)
#pragma unroll
      for (int n = 0; n < 4; ++n) acc[mh][mi][n] = (f32x4){0.f, 0.f, 0.f, 0.f};

  bf16x8 ga[2][4], gba[2][2], gbb[2][2];
#define RD_A(BUF, H) { \
    ga[0][0] = dsr<(BUF)*32768 + (H)*16384 + 0>(aB0);    ga[0][1] = dsr<(BUF)*32768 + (H)*16384 + 2048>(aB0); \
    ga[0][2] = dsr<(BUF)*32768 + (H)*16384 + 4096>(aB0); ga[0][3] = dsr<(BUF)*32768 + (H)*16384 + 6144>(aB0); \
    ga[1][0] = dsr<(BUF)*32768 + (H)*16384 + 0>(aB1);    ga[1][1] = dsr<(BUF)*32768 + (H)*16384 + 2048>(aB1); \
    ga[1][2] = dsr<(BUF)*32768 + (H)*16384 + 4096>(aB1); ga[1][3] = dsr<(BUF)*32768 + (H)*16384 + 6144>(aB1); }
#define RD_B(BUF, H, GB) { \
    GB[0][0] = dsr<(BUF)*32768 + (H)*16384 + 0>(bB0); GB[0][1] = dsr<(BUF)*32768 + (H)*16384 + 2048>(bB0); \
    GB[1][0] = dsr<(BUF)*32768 + (H)*16384 + 0>(bB1); GB[1][1] = dsr<(BUF)*32768 + (H)*16384 + 2048>(bB1); }
#define SB0 __builtin_amdgcn_sched_barrier(0)
#define BAR __builtin_amdgcn_s_barrier()
#define MM(MH, NH, GB) { \
    __builtin_amdgcn_s_setprio(1); \
    _Pragma("unroll") \
    for (int mf = 0; mf < 4; ++mf) \
      _Pragma("unroll") \
      for (int j = 0; j < 2; ++j) { \
        acc[MH][mf][(NH)*2 + j] = __builtin_amdgcn_mfma_f32_16x16x32_bf16(ga[0][mf], GB[0][j], acc[MH][mf][(NH)*2 + j], 0, 0, 0); \
        acc[MH][mf][(NH)*2 + j] = __builtin_amdgcn_mfma_f32_16x16x32_bf16(ga[1][mf], GB[1][j], acc[MH][mf][(NH)*2 + j], 0, 0, 0); } \
    __builtin_amdgcn_s_setprio(0); }

#define ITER(T1, T2, T3, LAST) { \
    /* ph1 (mh0,nh0) buf0 */ \
    RD_B(0, 0, gba) RD_A(0, 0) \
    STG_A(1, T1, 1) \
    LGKM(8); \
    BAR; LGKM(0); SB0; \
    MM(0, 0, gba) \
    BAR; \
    /* ph2 (mh0,nh1) */ \
    RD_B(0, 1, gbb) \
    if (!(LAST)) STG_A(0, T2, 0) \
    BAR; LGKM(0); SB0; \
    MM(0, 1, gbb) \
    BAR; \
    /* ph3 (mh1,nh1) */ \
    RD_A(0, 1) \
    if (!(LAST)) STG_B(0, T2, 0) \
    BAR; LGKM(0); SB0; \
    MM(1, 1, gbb) \
    BAR; \
    /* ph4 (mh1,nh0) */ \
    if (!(LAST)) STG_B(1, T2, 0) \
    BAR; \
    MM(1, 0, gba) \
    if (LAST) { VMCNT(0); } else { VMCNT(6); } \
    BAR; \
    /* ph5 (mh0,nh0) buf1 */ \
    RD_B(1, 0, gba) RD_A(1, 0) \
    if (!(LAST)) STG_A(1, T2, 0) \
    LGKM(8); \
    BAR; LGKM(0); SB0; \
    MM(0, 0, gba) \
    BAR; \
    /* ph6 (mh0,nh1) */ \
    RD_B(1, 1, gbb) \
    if (!(LAST)) STG_A(0, T3, 1) \
    BAR; LGKM(0); SB0; \
    MM(0, 1, gbb) \
    BAR; \
    /* ph7 (mh1,nh1) */ \
    RD_A(1, 1) \
    if (!(LAST)) STG_B(0, T3, 1) \
    BAR; LGKM(0); SB0; \
    MM(1, 1, gbb) \
    BAR; \
    /* ph8 (mh1,nh0) */ \
    if (!(LAST)) STG_B(1, T3, 1) \
    BAR; \
    MM(1, 0, gba) \
    if (!(LAST)) { VMCNT(6); BAR; } }

  int NI = K >> 7;  // iterations, 2 K-tiles each
  // prologue: tile0 -> buf0 (A-mh0, B-a, B-b, A-mh1), tile1 -> buf1 (A-mh0, B-a, B-b)
  STG_A(0, 0, 0) STG_B(0, 0, 0) STG_B(1, 0, 0) STG_A(1, 0, 0)
  STG_A(0, 1, 1) STG_B(0, 1, 1) STG_B(1, 1, 1)
  VMCNT(6);
  BAR;

  for (int i = 0; i < NI - 1; ++i) {
    ITER(2 * i + 1, 2 * i + 2, 2 * i + 3, 0)
  }
  ITER(2 * NI - 1, 0, 0, 1)

#undef ITER
#undef MM
#undef BAR
#undef SB0
#undef RD_B
#undef RD_A
#undef STG_B
#undef STG_A

  // ---- epilogue ----
  int r0 = bm * 256 + wm * 128;
  int c0 = bn * 256 + wn * 64;
#pragma unroll
  for (int mh = 0; mh < 2; ++mh)
#pragma unroll
    for (int mi = 0; mi < 4; ++mi) {
      int rowb = r0 + mh * 64 + mi * 16 + ((lane >> 4) << 2);
#pragma unroll
      for (int r = 0; r < 4; ++r) {
        int row = rowb + r;
        if (DO_GELU) {
#pragma unroll
          for (int n = 0; n < 4; ++n) {
            int col = c0 + n * 16 + (lane & 15);
            Hout[((size_t)e * M + row) * N + col] = f2bf(gelu_tanh(acc[mh][mi][n][r]));
          }
        }
        if (FUSE_COMBINE) {
          int tkn = smap[e * CAP + row];
          if (tkn >= 0) {
            float g = gate[tkn];
#pragma unroll
            for (int n = 0; n < 4; ++n) {
              int col = c0 + n * 16 + (lane & 15);
              out[(size_t)tkn * Dd + col] = acc[mh][mi][n][r] * g;
            }
          }
        }
      }
    }
}

extern "C" void kernel_launch(void* const* d_in, const int* in_sizes, int n_in,
                              void* d_out, int out_size, void* d_ws, size_t ws_size,
                              hipStream_t stream) {
  const float* x  = (const float*)d_in[0];
  const float* wg = (const float*)d_in[1];
  const float* w1 = (const float*)d_in[2];
  const float* w2 = (const float*)d_in[3];
  float* out = (float*)d_out;

  char* ws = (char*)d_ws;
  int*   idx  = (int*)(ws + 0);
  int*   pos  = (int*)(ws + 65536);
  float* gate = (float*)(ws + 131072);
  float* meP  = (float*)(ws + 196608);
  int*   smap = (int*)(ws + 327680);
  int*   cnt  = (int*)(ws + 393216);
  int*   base = (int*)(ws + 395264);
  unsigned short* Xg  = (unsigned short*)(ws + 401408ull);
  unsigned short* W1T = (unsigned short*)(ws + 33955840ull);
  unsigned short* W2T = (unsigned short*)(ws + 101064704ull);
  unsigned short* H   = (unsigned short*)(ws + 168173568ull);

  hipMemsetAsync(smap, 0xFF, Ee * CAP * 4, stream);
  gating_kernel<<<Tt / 4, 256, 0, stream>>>(x, wg, idx, gate, meP);
  count_kernel<<<Tt / 256, 256, 0, stream>>>(idx, cnt);
  prefix_kernel<<<1, 256, 0, stream>>>(cnt, base, meP, out + (size_t)Tt * Dd);
  assign_kernel<<<Tt / 256, 256, 0, stream>>>(idx, base, pos, smap);
  zero_dropped<<<256, 256, 0, stream>>>(pos, out);
  transpose_cast2<<<dim3(1024, 1, 16), 256, 0, stream>>>(w1, w2, W1T, W2T);
  build_xg<<<Ee * CAP, 256, 0, stream>>>(x, smap, Xg);
  gemm8p_kernel<1, 0><<<dim3(DFFf / 256, CAP / 256, Ee), 512, 0, stream>>>(
      Xg, W1T, H, nullptr, nullptr, nullptr, CAP, DFFf, Dd);
  gemm8p_kernel<0, 1><<<dim3(Dd / 256, CAP / 256, Ee), 512, 0, stream>>>(
      H, W2T, nullptr, smap, gate, out, CAP, Dd, DFFf);
}

// Round 14
// 459.170 us; speedup vs baseline: 1.1358x; 1.0336x over previous
//
#include <hip/hip_runtime.h>
#include <hip/hip_bf16.h>

#define Tt   16384
#define Dd   1024
#define Ee   8
#define CAP  2048
#define DFFf 4096

typedef __attribute__((ext_vector_type(8))) short bf16x8;
typedef __attribute__((ext_vector_type(4))) float f32x4;

__device__ __forceinline__ unsigned short f2bf(float f) {
  union { float f; unsigned u; } v; v.f = f;
  unsigned r = (v.u + 0x7FFFu + ((v.u >> 16) & 1u)) >> 16;
  return (unsigned short)r;
}

__device__ __forceinline__ float gelu_tanh(float x) {
  float z = 0.7978845608028654f * (x + 0.044715f * x * x * x);
  float az = fabsf(z);
  float t = __expf(-2.0f * az);
  float th = (1.0f - t) / (1.0f + t);
  th = (z < 0.0f) ? -th : th;
  return 0.5f * x * (1.0f + th);
}

__device__ __forceinline__ void gld16(const void* g, void* l) {
  __builtin_amdgcn_global_load_lds(
      (const __attribute__((address_space(1))) void*)g,
      (__attribute__((address_space(3))) void*)l,
      16, 0, 0);
}

template <int IMM>
__device__ __forceinline__ bf16x8 dsr(unsigned a) {
  bf16x8 r;
  asm volatile("ds_read_b128 %0, %1 offset:%c2" : "=v"(r) : "v"(a), "i"(IMM));
  return r;
}
#define LGKM(N) asm volatile("s_waitcnt lgkmcnt(" #N ")" ::: "memory")
#define VMCNT(N) asm volatile("s_waitcnt vmcnt(" #N ")" ::: "memory")

// ---------------- gating: logits fp32, softmax, argmax ----------------
__global__ __launch_bounds__(256) void gating_kernel(
    const float* __restrict__ x, const float* __restrict__ wg,
    int* __restrict__ idx, float* __restrict__ gate, float* __restrict__ meP) {
  int tid = threadIdx.x, lane = tid & 63, w = tid >> 6;
  int t = blockIdx.x * 4 + w;
  const float* xr = x + (size_t)t * Dd;
  float p[8];
#pragma unroll
  for (int e2 = 0; e2 < 8; ++e2) p[e2] = 0.f;
#pragma unroll
  for (int i = 0; i < 16; ++i) {
    int j = lane + (i << 6);
    float xv = xr[j];
    const float4* wr = (const float4*)(wg + j * 8);
    float4 a = wr[0], b = wr[1];
    p[0] += xv * a.x; p[1] += xv * a.y; p[2] += xv * a.z; p[3] += xv * a.w;
    p[4] += xv * b.x; p[5] += xv * b.y; p[6] += xv * b.z; p[7] += xv * b.w;
  }
#pragma unroll
  for (int off = 32; off > 0; off >>= 1)
#pragma unroll
    for (int e2 = 0; e2 < 8; ++e2) p[e2] += __shfl_xor(p[e2], off);
  __shared__ float smG[4][8];
  if (lane == 0) {
    float mx = p[0]; int am = 0;
#pragma unroll
    for (int e2 = 1; e2 < 8; ++e2) if (p[e2] > mx) { mx = p[e2]; am = e2; }
    float s = 0.f, g2[8];
#pragma unroll
    for (int e2 = 0; e2 < 8; ++e2) { g2[e2] = __expf(p[e2] - mx); s += g2[e2]; }
    float inv = 1.f / s;
    idx[t] = am;
    gate[t] = g2[am] * inv;
#pragma unroll
    for (int e2 = 0; e2 < 8; ++e2) smG[w][e2] = g2[e2] * inv;
  }
  __syncthreads();
  if (tid < 8)
    meP[blockIdx.x * 8 + tid] = smG[0][tid] + smG[1][tid] + smG[2][tid] + smG[3][tid];
}

// ------------- parallel scan, stage 1: per-chunk expert counts -------------
__global__ __launch_bounds__(256) void count_kernel(
    const int* __restrict__ idx, int* __restrict__ cnt) {
  int tid = threadIdx.x, lane = tid & 63, w = tid >> 6;
  int e = idx[blockIdx.x * 256 + tid];
  __shared__ int c[4][8];
#pragma unroll
  for (int q = 0; q < 8; ++q) {
    unsigned long long m = __ballot(e == q);
    if (lane == 0) c[w][q] = (int)__popcll(m);
  }
  __syncthreads();
  if (tid < 8)
    cnt[blockIdx.x * 8 + tid] = c[0][tid] + c[1][tid] + c[2][tid] + c[3][tid];
}

// ------------- stage 2: exclusive prefix over chunks + l_aux + totals -------
__global__ __launch_bounds__(256) void prefix_kernel(
    const int* __restrict__ cnt, int* __restrict__ base,
    const float* __restrict__ meP, float* __restrict__ laux_out,
    int* __restrict__ etot) {
  int tid = threadIdx.x;
  __shared__ int tot[8];
  __shared__ float red[256];
  __shared__ float smes[8];
  if (tid < 8) {
    int run = 0;
    for (int b2 = 0; b2 < 64; ++b2) { base[b2 * 8 + tid] = run; run += cnt[b2 * 8 + tid]; }
    tot[tid] = run;
    etot[tid] = run;
  }
  float part = 0.f;
  int e2 = tid & 7, r0 = tid >> 3;
  for (int b2 = r0; b2 < 4096; b2 += 32) part += meP[b2 * 8 + e2];
  red[tid] = part;
  __syncthreads();
  if (tid < 8) {
    float s = 0.f;
    for (int i = 0; i < 32; ++i) s += red[i * 8 + tid];
    smes[tid] = s * (float)tot[tid];
  }
  __syncthreads();
  if (tid == 0) {
    float l = 0.f;
    for (int q = 0; q < 8; ++q) l += smes[q];
    laux_out[0] = l * 8.0f / ((float)Tt * (float)Tt);
  }
}

// ------------- stage 3: assign slots + fused dropped-row zeroing -------------
__global__ __launch_bounds__(256) void assign_kernel(
    const int* __restrict__ idx, const int* __restrict__ base,
    int* __restrict__ smap, float* __restrict__ out) {
  int tid = threadIdx.x, lane = tid & 63, w = tid >> 6;
  __shared__ int wc[4][8];
  __shared__ int dropN;
  __shared__ int dropL[256];
  if (tid == 0) dropN = 0;
  int t = blockIdx.x * 256 + tid;
  int e = idx[t];
  int myoff = 0;
#pragma unroll
  for (int q = 0; q < 8; ++q) {
    unsigned long long m = __ballot(e == q);
    if (lane == 0) wc[w][q] = (int)__popcll(m);
    if (e == q) myoff = (int)__popcll(m & ((1ull << lane) - 1ull));
  }
  __syncthreads();
  int b = base[blockIdx.x * 8 + e];
  for (int ww = 0; ww < w; ++ww) b += wc[ww][e];
  int p = b + myoff;
  if (p < CAP) {
    smap[e * CAP + p] = t;
  } else {
    int k = atomicAdd(&dropN, 1);
    dropL[k] = t;
  }
  __syncthreads();
  int nd = dropN;
  for (int k = 0; k < nd; ++k)
    ((float4*)(out + (size_t)dropL[k] * Dd))[tid] = make_float4(0.f, 0.f, 0.f, 0.f);
}

// ---- merged transpose + cast fp32 -> bf16; float4 loads, ushort4 stores ----
__global__ __launch_bounds__(256) void transpose_cast2(
    const float* __restrict__ w1, const float* __restrict__ w2,
    unsigned short* __restrict__ W1T, unsigned short* __restrict__ W2T) {
  __shared__ float tile[64][65];
  int z = blockIdx.z, tz = blockIdx.x;
  const float* s; unsigned short* d; int R, Cn, rb, cb;
  if (z < 8) {
    s = w1 + (size_t)z * Dd * DFFf; d = W1T + (size_t)z * Dd * DFFf;
    R = Dd; Cn = DFFf; rb = (tz >> 6) * 64; cb = (tz & 63) * 64;
  } else {
    s = w2 + (size_t)(z - 8) * DFFf * Dd; d = W2T + (size_t)(z - 8) * DFFf * Dd;
    R = DFFf; Cn = Dd; rb = (tz >> 4) * 64; cb = (tz & 15) * 64;
  }
  int tid = threadIdx.x;
  int c4 = (tid & 15) * 4;
  int r4 = tid >> 4;
#pragma unroll
  for (int i = 0; i < 4; ++i) {
    int r = r4 + i * 16;
    float4 v = *(const float4*)(s + (size_t)(rb + r) * Cn + cb + c4);
    tile[r][c4 + 0] = v.x; tile[r][c4 + 1] = v.y;
    tile[r][c4 + 2] = v.z; tile[r][c4 + 3] = v.w;
  }
  __syncthreads();
  int cc0 = (tid & 15) * 4;
  int rr0 = tid >> 4;
#pragma unroll
  for (int p = 0; p < 4; ++p) {
    int rr = rr0 + p * 16;
    ushort4 o;
    o.x = f2bf(tile[cc0 + 0][rr]);
    o.y = f2bf(tile[cc0 + 1][rr]);
    o.z = f2bf(tile[cc0 + 2][rr]);
    o.w = f2bf(tile[cc0 + 3][rr]);
    *(ushort4*)(d + (size_t)(cb + rr) * R + rb + cc0) = o;
  }
}

// ------------- gather + cast dispatched tokens (etot-guarded) -------------
__global__ __launch_bounds__(256) void build_xg(
    const float* __restrict__ x, const int* __restrict__ smap,
    const int* __restrict__ etot, unsigned short* __restrict__ Xg) {
  int row = blockIdx.x;
  int e = row >> 11, p = row & (CAP - 1);
  int t = (p < etot[e]) ? smap[row] : -1;
  int j = threadIdx.x;
  float4 v = make_float4(0.f, 0.f, 0.f, 0.f);
  if (t >= 0) v = ((const float4*)(x + (size_t)t * Dd))[j];
  ushort4 o;
  o.x = f2bf(v.x); o.y = f2bf(v.y); o.z = f2bf(v.z); o.w = f2bf(v.w);
  ((ushort4*)(Xg + (size_t)row * Dd))[j] = o;
}

// ------------- 256^2-tile bf16 MFMA GEMM (B^T), counted-vmcnt dbuf (r6) -----
// 8 waves (2M x 4N), per-wave 128x64, BK=64, dbuf LDS, 0-conflict XOR layout.
// Staging split P0/P1/P2; waits vmcnt(4)@P1 (>=2-phase cover), vmcnt(2)@P3;
// never 0 in steady loop. ds_read groups pipelined with counted lgkm 8/4/4/0.
// Converged config: 810 TF = 90% of the 2-barrier-structure ceiling (m97/m131-141).
template <int DO_GELU, int FUSE_COMBINE>
__global__ __launch_bounds__(512, 2) void gemm256_kernel(
    const unsigned short* __restrict__ A,   // [E][M][K] bf16
    const unsigned short* __restrict__ BT,  // [E][N][K] bf16
    unsigned short* __restrict__ Hout,      // [E][M][N] bf16 (GEMM1)
    const int* __restrict__ smap,           // [E][CAP] token map (GEMM2)
    const int* __restrict__ etot,           // [E] expert totals (GEMM2)
    const float* __restrict__ gate,         // [T]
    float* __restrict__ out,                // [T][D]
    int M, int N, int K) {
  __shared__ unsigned short lds[2][2][16384];  // [buf][A/B][256 rows x 64 k]
  int tid = threadIdx.x, lane = tid & 63, w = tid >> 6;
  int wm = w >> 2, wn = w & 3;

  // bijective XCD-aware swizzle (nwg % 8 == 0)
  int gx = gridDim.x, gy = gridDim.y;
  long gid = blockIdx.x + (long)gx * (blockIdx.y + (long)gy * blockIdx.z);
  int nT = gx * gy * (int)gridDim.z;
  int cpx = nT >> 3;
  int swz = (int)((gid & 7) * (long)cpx + (gid >> 3));
  int bn = swz % gx;
  int bm = (swz / gx) % gy;
  int e  = swz / (gx * gy);

  const unsigned short* Ab = A + ((size_t)e * M + (size_t)bm * 256) * K;
  const unsigned short* Bb = BT + ((size_t)e * N + (size_t)bn * 256) * K;

  // phys p holds logical p ^ (((p>>7)&7)<<4) (involution, both-sides swizzle)
  auto stageB = [&](const unsigned short* src, unsigned short* L, int h) {
#pragma unroll
    for (int q = 0; q < 2; ++q) {
      int p = h * 16384 + q * 8192 + tid * 16;
      int lg = p ^ (((p >> 7) & 7) << 4);
      gld16(src + (size_t)(lg >> 7) * K + ((lg & 127) >> 1),
            (unsigned short*)((char*)L + p));
    }
  };
  auto stageA = [&](const unsigned short* src, unsigned short* L, int h) {
#pragma unroll
    for (int q = 0; q < 2; ++q) {
      int p = q * 16384 + h * 8192 + tid * 16;
      int lg = p ^ (((p >> 7) & 7) << 4);
      gld16(src + (size_t)(lg >> 7) * K + ((lg & 127) >> 1),
            (unsigned short*)((char*)L + p));
    }
  };

  f32x4 acc[2][4][4];
#pragma unroll
  for (int mh = 0; mh < 2; ++mh)
#pragma unroll
    for (int mi = 0; mi < 4; ++mi)
#pragma unroll
      for (int n = 0; n < 4; ++n) acc[mh][mi][n] = (f32x4){0.f, 0.f, 0.f, 0.f};

  auto mfma16 = [&](f32x4 (*ac)[4], const bf16x8* av, const bf16x8* bv) {
#pragma unroll
    for (int mi = 0; mi < 4; ++mi)
#pragma unroll
      for (int n = 0; n < 4; ++n)
        ac[mi][n] = __builtin_amdgcn_mfma_f32_16x16x32_bf16(av[mi], bv[n], ac[mi][n], 0, 0, 0);
  };

  unsigned lbase = (unsigned)(size_t)(__attribute__((address_space(3))) unsigned short*)&lds[0][0][0];
  int arow = wm * 128 + (lane & 15);
  int brow = wn * 64 + (lane & 15);
  unsigned kc2 = (unsigned)(((lane >> 4) << 3) << 1);
  unsigned swA = (unsigned)((arow & 7) << 4), swB = (unsigned)((brow & 7) << 4);
  unsigned ak0 = lbase + ((((unsigned)arow << 7) + kc2) ^ swA);
  unsigned ak1 = lbase + ((((unsigned)arow << 7) + 64 + kc2) ^ swA);
  unsigned bk0 = lbase + 32768u + ((((unsigned)brow << 7) + kc2) ^ swB);
  unsigned bk1 = lbase + 32768u + ((((unsigned)brow << 7) + 64 + kc2) ^ swB);

  bf16x8 a0[4], a1[4], a2[4], a3[4], b0[4], b1[4];
#define G0_ { \
    b0[0] = dsr<0>(bk0); b0[1] = dsr<2048>(bk0); b0[2] = dsr<4096>(bk0); b0[3] = dsr<6144>(bk0); \
    a0[0] = dsr<0>(ak0); a0[1] = dsr<2048>(ak0); a0[2] = dsr<4096>(ak0); a0[3] = dsr<6144>(ak0); }
#define G1_ { \
    b1[0] = dsr<0>(bk1); b1[1] = dsr<2048>(bk1); b1[2] = dsr<4096>(bk1); b1[3] = dsr<6144>(bk1); \
    a1[0] = dsr<0>(ak1); a1[1] = dsr<2048>(ak1); a1[2] = dsr<4096>(ak1); a1[3] = dsr<6144>(ak1); }
#define G2_ { \
    a2[0] = dsr<8192>(ak0); a2[1] = dsr<10240>(ak0); a2[2] = dsr<12288>(ak0); a2[3] = dsr<14336>(ak0); }
#define G3_ { \
    a3[0] = dsr<8192>(ak1); a3[1] = dsr<10240>(ak1); a3[2] = dsr<12288>(ak1); a3[3] = dsr<14336>(ak1); }
#define SB0 __builtin_amdgcn_sched_barrier(0)
#define PRIO_MFMA(AC, AV, BV) { \
    __builtin_amdgcn_s_setprio(1); mfma16(AC, AV, BV); __builtin_amdgcn_s_setprio(0); }

  int NT = K >> 6;
  stageB(Bb, lds[0][1], 0); stageB(Bb, lds[0][1], 1);
  stageA(Ab, lds[0][0], 0);
  stageA(Ab, lds[0][0], 1);
  VMCNT(2);
  __builtin_amdgcn_s_barrier();
  G0_

  for (int t = 0; t < NT - 1; ++t) {
    unsigned short* SA = lds[(t & 1) ^ 1][0];
    unsigned short* SB = lds[(t & 1) ^ 1][1];
    const unsigned short* An = Ab + ((t + 1) << 6);
    const unsigned short* Bn = Bb + ((t + 1) << 6);
    // ---- P0: reads G1; stage B(t+1); wait G0; MFMA a0xb0 ----
    G1_
    stageB(Bn, SB, 0); stageB(Bn, SB, 1);
    LGKM(8); SB0;
    PRIO_MFMA(acc[0], a0, b0);
    // ---- P1: drain A-h1(t); reads G2; stage A-h0(t+1); wait G1; MFMA a1xb1 ----
    VMCNT(4);
    __builtin_amdgcn_s_barrier();
    G2_
    stageA(An, SA, 0);
    LGKM(4); SB0;
    PRIO_MFMA(acc[0], a1, b1);
    // ---- P2: reads G3; stage A-h1(t+1); wait G2; MFMA a2xb0 ----
    G3_
    stageA(An, SA, 1);
    LGKM(4); SB0;
    PRIO_MFMA(acc[1], a2, b0);
    // ---- P3: wait G3; MFMA a3xb1; drain B+A-h0(t+1); swap; reads G0 ----
    LGKM(0); SB0;
    PRIO_MFMA(acc[1], a3, b1);
    VMCNT(2);
    __builtin_amdgcn_s_barrier();
    ak0 ^= 65536u; ak1 ^= 65536u; bk0 ^= 65536u; bk1 ^= 65536u;
    G0_
  }

  // ---- final tile: no staging; single vmcnt(0) at P1 ----
  G1_
  LGKM(8); SB0;
  PRIO_MFMA(acc[0], a0, b0);
  VMCNT(0);
  __builtin_amdgcn_s_barrier();
  G2_
  LGKM(4); SB0;
  PRIO_MFMA(acc[0], a1, b1);
  G3_
  LGKM(4); SB0;
  PRIO_MFMA(acc[1], a2, b0);
  LGKM(0); SB0;
  PRIO_MFMA(acc[1], a3, b1);

#undef G0_
#undef G1_
#undef G2_
#undef G3_
#undef SB0
#undef PRIO_MFMA

  // ---- epilogue ----
  int r0 = bm * 256 + wm * 128;
  int c0 = bn * 256 + wn * 64;
#pragma unroll
  for (int mh = 0; mh < 2; ++mh)
#pragma unroll
    for (int mi = 0; mi < 4; ++mi) {
      int rowb = r0 + mh * 64 + mi * 16 + ((lane >> 4) << 2);
#pragma unroll
      for (int r = 0; r < 4; ++r) {
        int row = rowb + r;
        if (DO_GELU) {
#pragma unroll
          for (int n = 0; n < 4; ++n) {
            int col = c0 + n * 16 + (lane & 15);
            Hout[((size_t)e * M + row) * N + col] = f2bf(gelu_tanh(acc[mh][mi][n][r]));
          }
        }
        if (FUSE_COMBINE) {
          int tkn = (row < etot[e]) ? smap[e * CAP + row] : -1;
          if (tkn >= 0) {
            float g = gate[tkn];
#pragma unroll
            for (int n = 0; n < 4; ++n) {
              int col = c0 + n * 16 + (lane & 15);
              out[(size_t)tkn * Dd + col] = acc[mh][mi][n][r] * g;
            }
          }
        }
      }
    }
}

extern "C" void kernel_launch(void* const* d_in, const int* in_sizes, int n_in,
                              void* d_out, int out_size, void* d_ws, size_t ws_size,
                              hipStream_t stream) {
  const float* x  = (const float*)d_in[0];
  const float* wg = (const float*)d_in[1];
  const float* w1 = (const float*)d_in[2];
  const float* w2 = (const float*)d_in[3];
  float* out = (float*)d_out;

  char* ws = (char*)d_ws;
  int*   idx  = (int*)(ws + 0);
  float* gate = (float*)(ws + 131072);
  float* meP  = (float*)(ws + 196608);
  int*   smap = (int*)(ws + 327680);
  int*   cnt  = (int*)(ws + 393216);
  int*   base = (int*)(ws + 395264);
  int*   etot = (int*)(ws + 397312);
  unsigned short* Xg  = (unsigned short*)(ws + 401408ull);
  unsigned short* W1T = (unsigned short*)(ws + 33955840ull);
  unsigned short* W2T = (unsigned short*)(ws + 101064704ull);
  unsigned short* H   = (unsigned short*)(ws + 168173568ull);

  gating_kernel<<<Tt / 4, 256, 0, stream>>>(x, wg, idx, gate, meP);
  count_kernel<<<Tt / 256, 256, 0, stream>>>(idx, cnt);
  prefix_kernel<<<1, 256, 0, stream>>>(cnt, base, meP, out + (size_t)Tt * Dd, etot);
  assign_kernel<<<Tt / 256, 256, 0, stream>>>(idx, base, smap, out);
  transpose_cast2<<<dim3(1024, 1, 16), 256, 0, stream>>>(w1, w2, W1T, W2T);
  build_xg<<<Ee * CAP, 256, 0, stream>>>(x, smap, etot, Xg);
  gemm256_kernel<1, 0><<<dim3(DFFf / 256, CAP / 256, Ee), 512, 0, stream>>>(
      Xg, W1T, H, nullptr, nullptr, nullptr, nullptr, CAP, DFFf, Dd);
  gemm256_kernel<0, 1><<<dim3(Dd / 256, CAP / 256, Ee), 512, 0, stream>>>(
      H, W2T, nullptr, smap, etot, gate, out, CAP, Dd, DFFf);
}